// Round 8
// baseline (86.327 us; speedup 1.0000x reference)
//
#include <hip/hip_runtime.h>

typedef _Float16 half8  __attribute__((ext_vector_type(8)));
typedef _Float16 half4h __attribute__((ext_vector_type(4)));
typedef float    f32x4  __attribute__((ext_vector_type(4)));

#define B_     8
#define D_     1024
#define G_     32
#define K_     64
#define NP_    1024
#define ROWS   16
#define TPB    512
#define STRIDE 1028            // halfs per zh row (rows 8B-aligned)

__global__ __launch_bounds__(TPB, 4) void fitness(
    const float* __restrict__ x,
    const float* __restrict__ weights,
    const float* __restrict__ xopt,
    const float* __restrict__ R,
    const int* __restrict__ gidx,
    const int* __restrict__ mask,     // numpy bool -> int32
    const int* __restrict__ counts,
    float* __restrict__ out) {
  __shared__ _Float16 zh[ROWS * STRIDE];   // 32.9 KB
  __shared__ int      gli[G_ * K_];        // 8 KB
  __shared__ _Float16 Rb[8 * 512];         // 8 KB, B-fragment order
  __shared__ float    ctab[K_];
  __shared__ float    red[8][ROWS];        // per-wave row partials (atomic-free)

  const int tile = blockIdx.x;             // 0..63
  const int b    = blockIdx.y;             // 0..7
  const int t    = threadIdx.x;
  const int cnt  = counts[b];

  // ---- stage gather indices (2048 ints via int4) ----
  ((int4*)gli)[t] = ((const int4*)(gidx + b * (G_ * K_)))[t];

  if (t < K_) ctab[t] = exp2f((float)t * (19.931568569324174f / 63.0f));

  // ---- stage R -> B-fragment order fp16 (8 halfs per thread) ----
  {
    int pos  = t * 8;                      // 0..4095
    int frag = pos >> 9, rem = pos & 511;
    int lid  = rem >> 3;
    int kt = frag >> 2, nt = frag & 3;
    int quad = lid >> 4, ln = lid & 15;
    const float* rp = R + (kt * 32 + quad * 8) * K_ + nt * 16 + ln;
    half8 rv;
#pragma unroll
    for (int e = 0; e < 8; ++e) rv[e] = (_Float16)rp[e * K_];
    *(half8*)(Rb + pos) = rv;
  }

  // ---- stage z = x - xopt as fp16, coalesced float4 ----
  {
    const float4* x4  = (const float4*)(x + ((size_t)(b * NP_ + tile * ROWS)) * D_);
    const float4* xo4 = (const float4*)(xopt + b * D_);
    const int col4 = t & 255;
    float4 xo = xo4[col4];
#pragma unroll
    for (int j = 0; j < 8; ++j) {
      int row = (t >> 8) + 2 * j;
      float4 xv = x4[row * 256 + col4];
      half4h hv;
      hv[0] = (_Float16)(xv.x - xo.x);
      hv[1] = (_Float16)(xv.y - xo.y);
      hv[2] = (_Float16)(xv.z - xo.z);
      hv[3] = (_Float16)(xv.w - xo.w);
      *(half4h*)(zh + row * STRIDE + col4 * 4) = hv;
    }
  }
  __syncthreads();

  const int wv   = t >> 6;                 // 0..7
  const int lane = t & 63;
  const int quad = lane >> 4;
  const int ln   = lane & 15;

  // R fragments -> registers (block-invariant)
  half8 rb[8];
#pragma unroll
  for (int f = 0; f < 8; ++f) rb[f] = *(const half8*)(Rb + f * 512 + lane * 8);

  float cl0 = ctab[ln], cl1 = ctab[ln + 16], cl2 = ctab[ln + 32], cl3 = ctab[ln + 48];

  const _Float16* zr = zh + ln * STRIDE;   // this lane's z row (row = ln)
  float q0 = 0.f, q1 = 0.f, q2 = 0.f, q3 = 0.f;

  // ---- software-pipelined item loop: gather(g+8) overlaps MFMA/epilogue(g) ----
#define GATHER(gg, A0, A1)                                                  \
  {                                                                         \
    const int* gp = gli + (gg) * K_ + quad * 8;                             \
    int4 i0 = *(const int4*)(gp);                                           \
    int4 i1 = *(const int4*)(gp + 4);                                       \
    int4 i2 = *(const int4*)(gp + 32);                                      \
    int4 i3 = *(const int4*)(gp + 36);                                      \
    A0[0] = zr[i0.x]; A0[1] = zr[i0.y]; A0[2] = zr[i0.z]; A0[3] = zr[i0.w]; \
    A0[4] = zr[i1.x]; A0[5] = zr[i1.y]; A0[6] = zr[i1.z]; A0[7] = zr[i1.w]; \
    A1[0] = zr[i2.x]; A1[1] = zr[i2.y]; A1[2] = zr[i2.z]; A1[3] = zr[i2.w]; \
    A1[4] = zr[i3.x]; A1[5] = zr[i3.y]; A1[6] = zr[i3.z]; A1[7] = zr[i3.w]; \
  }

  half8 a0, a1;
  int g = wv;
  if (g < cnt) GATHER(g, a0, a1);
  while (g < cnt) {
    const int gn = g + 8;

    // epilogue operands for current g (L2-hot)
    const int* mg = mask + (b * G_ + g) * K_ + ln;
    int   m0 = mg[0], m1 = mg[16], m2 = mg[32], m3 = mg[48];
    float w  = weights[b * G_ + g];

    half8 b0 = a0, b1 = a1;
    if (gn < cnt) GATHER(gn, a0, a1);      // prefetch next item's fragments

    f32x4 c0 = {0.f, 0.f, 0.f, 0.f}, c1 = c0, c2 = c0, c3 = c0;
    c0 = __builtin_amdgcn_mfma_f32_16x16x32_f16(b0, rb[0], c0, 0, 0, 0);
    c1 = __builtin_amdgcn_mfma_f32_16x16x32_f16(b0, rb[1], c1, 0, 0, 0);
    c2 = __builtin_amdgcn_mfma_f32_16x16x32_f16(b0, rb[2], c2, 0, 0, 0);
    c3 = __builtin_amdgcn_mfma_f32_16x16x32_f16(b0, rb[3], c3, 0, 0, 0);
    c0 = __builtin_amdgcn_mfma_f32_16x16x32_f16(b1, rb[4], c0, 0, 0, 0);
    c1 = __builtin_amdgcn_mfma_f32_16x16x32_f16(b1, rb[5], c1, 0, 0, 0);
    c2 = __builtin_amdgcn_mfma_f32_16x16x32_f16(b1, rb[6], c2, 0, 0, 0);
    c3 = __builtin_amdgcn_mfma_f32_16x16x32_f16(b1, rb[7], c3, 0, 0, 0);

    float w0 = m0 ? w * cl0 : 0.0f;
    float w1 = m1 ? w * cl1 : 0.0f;
    float w2 = m2 ? w * cl2 : 0.0f;
    float w3 = m3 ? w * cl3 : 0.0f;

    q0 += w0 * c0[0] * c0[0] + w1 * c1[0] * c1[0] + w2 * c2[0] * c2[0] + w3 * c3[0] * c3[0];
    q1 += w0 * c0[1] * c0[1] + w1 * c1[1] * c1[1] + w2 * c2[1] * c2[1] + w3 * c3[1] * c3[1];
    q2 += w0 * c0[2] * c0[2] + w1 * c1[2] * c1[2] + w2 * c2[2] * c2[2] + w3 * c3[2] * c3[2];
    q3 += w0 * c0[3] * c0[3] + w1 * c1[3] * c1[3] + w2 * c2[3] * c2[3] + w3 * c3[3] * c3[3];

    g = gn;
  }
#undef GATHER

  // reduce over the 16 cols (ln) per wave; xor<16 stays within the quad
#pragma unroll
  for (int off = 1; off < 16; off <<= 1) {
    q0 += __shfl_xor(q0, off);
    q1 += __shfl_xor(q1, off);
    q2 += __shfl_xor(q2, off);
    q3 += __shfl_xor(q3, off);
  }
  if (ln == 0) {                           // one lane per quad -> rows quad*4+0..3
    float* rr = red[wv] + quad * 4;
    bool had = (wv < cnt);
    rr[0] = had ? q0 : 0.0f;
    rr[1] = had ? q1 : 0.0f;
    rr[2] = had ? q2 : 0.0f;
    rr[3] = had ? q3 : 0.0f;
  }
  __syncthreads();

  if (t < ROWS) {
    float s = 0.0f;
#pragma unroll
    for (int w2 = 0; w2 < 8; ++w2) s += red[w2][t];
    out[b * NP_ + tile * ROWS + t] = s;
  }
}

extern "C" void kernel_launch(void* const* d_in, const int* in_sizes, int n_in,
                              void* d_out, int out_size, void* d_ws, size_t ws_size,
                              hipStream_t stream) {
  const float* x       = (const float*)d_in[0];   // (B,NP,D)
  const float* weights = (const float*)d_in[1];   // (B,G)
  const float* xopt    = (const float*)d_in[2];   // (B,D)
  const float* R       = (const float*)d_in[3];   // (K,K)
  const int*   gidx    = (const int*)d_in[4];     // (B,G,K)
  const int*   mask    = (const int*)d_in[5];     // (B,G,K) bool -> int32
  const int*   counts  = (const int*)d_in[6];     // (B,)
  float*       out     = (float*)d_out;           // (B,NP)

  fitness<<<dim3(NP_ / ROWS, B_), dim3(TPB), 0, stream>>>(
      x, weights, xopt, R, gidx, mask, counts, out);
}